// Round 1
// baseline (378.474 us; speedup 1.0000x reference)
//
#include <hip/hip_runtime.h>

// Problem: x (32, 2, 24, 32768) f32 -> out (32, 2, 30, 32768) f32
// out[b,c,t,l] = mean over the 3 channels of triangle t.
// Purely HBM-bound: hold all 24 channel values per l in registers,
// emit all 30 triangle means -> input read exactly once.

#define L_DIM   32768
#define L4_DIM  (L_DIM / 4)   // 8192 float4 per channel row
#define NCH     24
#define NTRI    30
#define BLOCK   256

// Triangle table (compile-time so the t-loop folds to register adds).
constexpr int TA[NTRI] = {0,0,1,1,2,3,4,4,5,5,7,7,8,8,9,10,11,11,12,12,14,14,15,15,16,17,18,18,19,19};
constexpr int TB[NTRI] = {3,1,4,2,5,4,7,5,8,6,10,8,11,9,12,11,14,12,15,13,17,15,18,16,19,18,21,19,22,20};
constexpr int TC[NTRI] = {4,4,5,5,6,7,8,8,9,9,11,11,12,12,13,14,15,15,16,16,18,18,19,19,20,21,22,22,23,23};

__global__ __launch_bounds__(BLOCK) void tri_mean_kernel(
    const float* __restrict__ x, float* __restrict__ out)
{
    const int l4 = blockIdx.x * BLOCK + threadIdx.x;   // float4 index in [0, L4_DIM)
    const int bc = blockIdx.y;                          // (b*2 + c) in [0, 64)

    const float4* __restrict__ xin = (const float4*)(x + (size_t)bc * NCH * L_DIM);
    float4* __restrict__ o = (float4*)(out + (size_t)bc * NTRI * L_DIM);

    // Load all 24 channels' float4 at this l4 into registers (coalesced,
    // 16 B/lane, each channel row read exactly once across the grid).
    float4 v[NCH];
#pragma unroll
    for (int c = 0; c < NCH; ++c) {
        v[c] = xin[(size_t)c * L4_DIM + l4];
    }

    const float k = 1.0f / 3.0f;
#pragma unroll
    for (int t = 0; t < NTRI; ++t) {
        const float4 a = v[TA[t]];
        const float4 b = v[TB[t]];
        const float4 c = v[TC[t]];
        float4 r;
        r.x = (a.x + b.x + c.x) * k;
        r.y = (a.y + b.y + c.y) * k;
        r.z = (a.z + b.z + c.z) * k;
        r.w = (a.w + b.w + c.w) * k;
        o[(size_t)t * L4_DIM + l4] = r;
    }
}

extern "C" void kernel_launch(void* const* d_in, const int* in_sizes, int n_in,
                              void* d_out, int out_size, void* d_ws, size_t ws_size,
                              hipStream_t stream) {
    const float* x = (const float*)d_in[0];
    float* out = (float*)d_out;

    dim3 block(BLOCK);
    dim3 grid(L4_DIM / BLOCK, 64);  // 32 x 64 = 2048 blocks
    tri_mean_kernel<<<grid, block, 0, stream>>>(x, out);
}